// Round 9
// baseline (705.357 us; speedup 1.0000x reference)
//
#include <hip/hip_runtime.h>
#include <stdint.h>

typedef unsigned short u16;
typedef __bf16 bf16x8 __attribute__((ext_vector_type(8)));
typedef float f32x4 __attribute__((ext_vector_type(4)));

#define B_ 8
#define T_ 1024
#define C_ 1024
#define H_ 16
#define D_ 64
#define QKS 3072   // fused qkv row stride

__device__ __forceinline__ u16 f2bf(float f) {
  union { float f; unsigned u; } c; c.f = f;
  unsigned u = c.u;
  return (u16)((u + 0x7FFFu + ((u >> 16) & 1u)) >> 16);
}

__device__ __forceinline__ void g2l16(const void* g, void* l) {
  __builtin_amdgcn_global_load_lds((const __attribute__((address_space(1))) void*)g,
                                   (__attribute__((address_space(3))) void*)l, 16, 0, 0);
}

// ---------- transpose f32 [R][C] -> bf16 [C][R] ----------
__global__ __launch_bounds__(256) void trans_f32_bf16(const float* __restrict__ in,
                                                      u16* __restrict__ out, int R, int C) {
  __shared__ float t[32][33];
  int c0 = blockIdx.x * 32, r0 = blockIdx.y * 32;
  int tx = threadIdx.x & 31, ty = threadIdx.x >> 5;
#pragma unroll
  for (int i = ty; i < 32; i += 8)
    t[i][tx] = in[(size_t)(r0 + i) * C + c0 + tx];
  __syncthreads();
#pragma unroll
  for (int i = ty; i < 32; i += 8)
    out[(size_t)(c0 + i) * R + r0 + tx] = f2bf(t[tx][i]);
}

// ---------- transpose V: qkv [B*T][3072] (v section) -> vt [B*H][D][T] ----------
__global__ __launch_bounds__(256) void vtrans_bf16(const u16* __restrict__ qkv,
                                                   u16* __restrict__ vt) {
  __shared__ u16 t[64][66];
  int bh = blockIdx.y;
  int b = bh >> 4, h = bh & 15;
  int t0 = blockIdx.x * 64;
  int tx = threadIdx.x & 63, w = threadIdx.x >> 6;
#pragma unroll
  for (int i = w; i < 64; i += 4)
    t[i][tx] = qkv[(size_t)(b * T_ + t0 + i) * QKS + 2048 + h * D_ + tx];
  __syncthreads();
#pragma unroll
  for (int d = w; d < 64; d += 4)
    vt[((size_t)bh * D_ + d) * T_ + t0 + tx] = t[tx][d];
}

// ---------- layernorm f32 [rows][1024] -> bf16 ----------
__global__ __launch_bounds__(256) void ln_f32_bf16(const float* __restrict__ x,
                                                   const float* __restrict__ g,
                                                   const float* __restrict__ bt,
                                                   u16* __restrict__ out) {
  int row = blockIdx.x, tid = threadIdx.x;
  const float4* xr = (const float4*)(x + (size_t)row * C_);
  float4 a = xr[tid];
  float s = a.x + a.y + a.z + a.w;
  float ss = a.x * a.x + a.y * a.y + a.z * a.z + a.w * a.w;
#pragma unroll
  for (int m = 1; m < 64; m <<= 1) { s += __shfl_xor(s, m); ss += __shfl_xor(ss, m); }
  __shared__ float red[8];
  int wave = tid >> 6, lane = tid & 63;
  if (lane == 0) { red[wave] = s; red[wave + 4] = ss; }
  __syncthreads();
  s = red[0] + red[1] + red[2] + red[3];
  ss = red[4] + red[5] + red[6] + red[7];
  float mean = s * (1.0f / C_);
  float rstd = rsqrtf(ss * (1.0f / C_) - mean * mean + 1e-5f);
  float4 gg = ((const float4*)g)[tid];
  float4 bb = ((const float4*)bt)[tid];
  u16* op = out + (size_t)row * C_ + tid * 4;
  op[0] = f2bf((a.x - mean) * rstd * gg.x + bb.x);
  op[1] = f2bf((a.y - mean) * rstd * gg.y + bb.y);
  op[2] = f2bf((a.z - mean) * rstd * gg.z + bb.z);
  op[3] = f2bf((a.w - mean) * rstd * gg.w + bb.w);
}

// ---------- GEMM 256x256 tile, 8 waves (2M x 4N), BK=32, counted-vmcnt dbuf ----------
// A[M][K] bf16 @ (BT[N][K])^T. LDS chunk-swizzled (slot = chunk ^ (row&3), 16B chunks),
// applied on staging SOURCE + read XOR (involution). Loads ride across barriers: at tile
// top issue next tile's 4 loads, then s_waitcnt vmcnt(4) = current tile landed, next in
// flight (T4). Raw s_barrier (no vmcnt drain). setprio around MFMA clusters (T5).
// EPI 0: plain -> bf16.  EPI 1: +bias, relu -> bf16.  EPI 2: +bias +resid -> f32.
template <int EPI>
__global__ __launch_bounds__(512, 2) void gemm256(const u16* __restrict__ A,
                                                  const u16* __restrict__ BT,
                                                  u16* __restrict__ outb, float* __restrict__ outf,
                                                  const float* __restrict__ bias,
                                                  const float* __restrict__ resid,
                                                  int M, int N, int K) {
  __shared__ __attribute__((aligned(16))) u16 Abuf[2][256 * 32];
  __shared__ __attribute__((aligned(16))) u16 Bbuf[2][256 * 32];
  const int tid = threadIdx.x, wave = tid >> 6, lane = tid & 63;
  const int l15 = lane & 15, g = lane >> 4;
  const int wr = wave >> 2, wc = wave & 3;     // 2M x 4N wave grid
  const int m0 = blockIdx.y * 256, n0 = blockIdx.x * 256;
  // staging: per tile 1024 chunks(16B)/operand; thread t covers chunks {t, 512+t}.
  // chunk c: row = c>>2, slot cc = c&3; LDS[row][cc] holds global chunk cc^(row&3).
  const int srow = tid >> 2;
  const int sc = (tid & 3) ^ (srow & 3);
  const u16* a0 = A + (size_t)(m0 + srow) * K + sc * 8;
  const u16* b0 = BT + (size_t)(n0 + srow) * K + sc * 8;
  const int dst = wave * 512;                  // + j*4096 (u16)
  const int rsw = l15 & 3;                     // read-side xor
  const int NT = K >> 5;

  // prologue: stage tile 0 into buf 0 (4 loads/thread: 2 A + 2 B)
#pragma unroll
  for (int j = 0; j < 2; j++) {
    g2l16(a0 + (size_t)j * 128 * K, Abuf[0] + j * 4096 + dst);
    g2l16(b0 + (size_t)j * 128 * K, Bbuf[0] + j * 4096 + dst);
  }
  f32x4 acc[8][4] = {};
  for (int kt = 0; kt < NT; ++kt) {
    const int cur = kt & 1;
    if (kt + 1 < NT) {
      const size_t ko = (size_t)(kt + 1) * 32;
#pragma unroll
      for (int j = 0; j < 2; j++) {
        g2l16(a0 + (size_t)j * 128 * K + ko, Abuf[cur ^ 1] + j * 4096 + dst);
        g2l16(b0 + (size_t)j * 128 * K + ko, Bbuf[cur ^ 1] + j * 4096 + dst);
      }
      asm volatile("s_waitcnt vmcnt(4)" ::: "memory");  // tile kt landed; kt+1 in flight
    } else {
      asm volatile("s_waitcnt vmcnt(0)" ::: "memory");
    }
    __builtin_amdgcn_s_barrier();
    const u16* ab = Abuf[cur];
    const u16* bb = Bbuf[cur];
    bf16x8 bfr[4];
#pragma unroll
    for (int nn = 0; nn < 4; nn++)
      bfr[nn] = *(const bf16x8*)(bb + (wc * 64 + nn * 16 + l15) * 32 + ((g ^ rsw) * 8));
#pragma unroll
    for (int q = 0; q < 4; q++) {
      bf16x8 af[2];
#pragma unroll
      for (int i = 0; i < 2; i++)
        af[i] = *(const bf16x8*)(ab + (wr * 128 + (2 * q + i) * 16 + l15) * 32 + ((g ^ rsw) * 8));
      __builtin_amdgcn_s_setprio(1);
#pragma unroll
      for (int i = 0; i < 2; i++)
#pragma unroll
        for (int nn = 0; nn < 4; nn++)
          acc[2 * q + i][nn] =
              __builtin_amdgcn_mfma_f32_16x16x32_bf16(af[i], bfr[nn], acc[2 * q + i][nn], 0, 0, 0);
      __builtin_amdgcn_s_setprio(0);
    }
    __builtin_amdgcn_s_barrier();   // all reads of buf[cur] done before next overwrite
  }
  // epilogue
#pragma unroll
  for (int mm = 0; mm < 8; mm++)
#pragma unroll
    for (int nn = 0; nn < 4; nn++)
#pragma unroll
      for (int r = 0; r < 4; r++) {
        int row = m0 + wr * 128 + mm * 16 + g * 4 + r;
        int col = n0 + wc * 64 + nn * 16 + l15;
        float v = acc[mm][nn][r];
        if (EPI == 0) {
          outb[(size_t)row * N + col] = f2bf(v);
        } else if (EPI == 1) {
          v += bias[col];
          v = fmaxf(v, 0.f);
          outb[(size_t)row * N + col] = f2bf(v);
        } else {
          v += bias[col] + resid[(size_t)row * N + col];
          outf[(size_t)row * N + col] = v;
        }
      }
}

// ---------- flash attention, LDS double-buffered pipeline ----------
// qkv bf16 [B*T][3072] (q at col 0, k at col 1024); vt [B*H][D][T]; KVBLK=64.
__global__ __launch_bounds__(256) void attn_kernel(const u16* __restrict__ qkv,
                                                   const u16* __restrict__ vt,
                                                   const int* __restrict__ mask,
                                                   u16* __restrict__ o) {
  __shared__ __attribute__((aligned(16))) u16 kbuf[2][64 * 64];
  __shared__ __attribute__((aligned(16))) u16 vbuf[2][64 * 64];
  __shared__ __attribute__((aligned(16))) u16 plds[4][16 * 72];

  int tid = threadIdx.x, wave = tid >> 6, lane = tid & 63;
  int qt = blockIdx.x;           // 0..15  (64 q rows per block)
  int bh = blockIdx.y;           // 0..127
  int b = bh >> 4, h = bh & 15;
  int l15 = lane & 15, g = lane >> 4;

  int qrow = qt * 64 + wave * 16 + l15;
  int dk = g * 8;
  const u16* qp = qkv + (size_t)(b * T_ + qrow) * QKS + h * D_;
  bf16x8 qf0 = *(const bf16x8*)(qp + dk);
  bf16x8 qf1 = *(const bf16x8*)(qp + dk + 32);

  const u16* vtb = vt + (size_t)bh * D_ * T_;   // [64][1024]
  const size_t kbase = (size_t)(b * T_) * QKS + 1024 + h * D_;

  // staging geometry: 512 chunks of 16B per tile; thread handles chunks tid, 256+tid.
  // LDS slot (row r, chunk cc) holds global chunk cc ^ (r&7)  (involutive swizzle).
  int c0 = tid, r0s = c0 >> 3, cc0 = c0 & 7, sc0 = cc0 ^ (r0s & 7);
  int c1 = 256 + tid, r1s = c1 >> 3, cc1 = c1 & 7, sc1 = cc1 ^ (r1s & 7);
  const u16* ksrc0 = qkv + kbase + (size_t)r0s * QKS + sc0 * 8;
  const u16* ksrc1 = qkv + kbase + (size_t)r1s * QKS + sc1 * 8;
  const u16* vsrc0 = vtb + (size_t)r0s * T_ + sc0 * 8;
  const u16* vsrc1 = vtb + (size_t)r1s * T_ + sc1 * 8;
  int dst0 = (0 * 256 + wave * 64) * 8;
  int dst1 = (1 * 256 + wave * 64) * 8;

  f32x4 oacc[4] = {};
  float mrun[4], lrun[4];
#pragma unroll
  for (int r = 0; r < 4; r++) { mrun[r] = -1e30f; lrun[r] = 0.f; }

  u16* pw = plds[wave];
  const int wsw = g * 8;                  // P write xor
  const int rsw = ((l15 >> 2) & 3) * 8;   // P read xor
  const int swz0 = (g ^ (l15 & 7)) * 8;        // K/V tile read swizzle, chunk g
  const int swz1 = ((g + 4) ^ (l15 & 7)) * 8;  // chunk g+4

  // prologue: stage tile 0 into buf 0
  {
    g2l16(ksrc0, kbuf[0] + dst0);
    g2l16(ksrc1, kbuf[0] + dst1);
    g2l16(vsrc0, vbuf[0] + dst0);
    g2l16(vsrc1, vbuf[0] + dst1);
  }
  asm volatile("s_waitcnt vmcnt(0)" ::: "memory");
  __syncthreads();

  for (int kt = 0; kt < T_ / 64; ++kt) {
    int cur = kt & 1;
    // ---- issue stage of tile kt+1 into buf cur^1 ----
    if (kt < T_ / 64 - 1) {
      int nxt = cur ^ 1;
      size_t ko = (size_t)(kt + 1) * 64 * QKS;
      size_t vo = (size_t)(kt + 1) * 64;
      g2l16(ksrc0 + ko, kbuf[nxt] + dst0);
      g2l16(ksrc1 + ko, kbuf[nxt] + dst1);
      g2l16(vsrc0 + vo, vbuf[nxt] + dst0);
      g2l16(vsrc1 + vo, vbuf[nxt] + dst1);
    }
    int mv[4];
#pragma unroll
    for (int c = 0; c < 4; c++) mv[c] = mask[b * T_ + kt * 64 + c * 16 + l15];

    // ---- S = Q K^T over 64 k-cols (4 chunks of 16), K from LDS ----
    const u16* kb = kbuf[cur];
    f32x4 s[4];
#pragma unroll
    for (int c = 0; c < 4; c++) {
      const u16* kp = kb + (c * 16 + l15) * 64;
      bf16x8 k0 = *(const bf16x8*)(kp + swz0);
      bf16x8 k1 = *(const bf16x8*)(kp + swz1);
      f32x4 a = {};
      a = __builtin_amdgcn_mfma_f32_16x16x32_bf16(qf0, k0, a, 0, 0, 0);
      a = __builtin_amdgcn_mfma_f32_16x16x32_bf16(qf1, k1, a, 0, 0, 0);
#pragma unroll
      for (int r = 0; r < 4; r++) a[r] = mv[c] ? a[r] * 0.125f : -1e30f;
      s[c] = a;
    }
    // ---- online softmax ----
    float tmax[4];
#pragma unroll
    for (int r = 0; r < 4; r++)
      tmax[r] = fmaxf(fmaxf(s[0][r], s[1][r]), fmaxf(s[2][r], s[3][r]));
#pragma unroll
    for (int m = 1; m < 16; m <<= 1)
#pragma unroll
      for (int r = 0; r < 4; r++) tmax[r] = fmaxf(tmax[r], __shfl_xor(tmax[r], m));
    float alpha[4];
#pragma unroll
    for (int r = 0; r < 4; r++) {
      float nm = fmaxf(mrun[r], tmax[r]);
      alpha[r] = __expf(mrun[r] - nm);
      mrun[r] = nm;
    }
    float psum[4] = {0.f, 0.f, 0.f, 0.f};
#pragma unroll
    for (int c = 0; c < 4; c++)
#pragma unroll
      for (int r = 0; r < 4; r++) {
        float p = __expf(s[c][r] - mrun[r]);
        s[c][r] = p;
        psum[r] += p;
      }
#pragma unroll
    for (int m = 1; m < 16; m <<= 1)
#pragma unroll
      for (int r = 0; r < 4; r++) psum[r] += __shfl_xor(psum[r], m);
#pragma unroll
    for (int r = 0; r < 4; r++) lrun[r] = lrun[r] * alpha[r] + psum[r];
#pragma unroll
    for (int n = 0; n < 4; n++)
#pragma unroll
      for (int r = 0; r < 4; r++) oacc[n][r] *= alpha[r];
    // ---- P -> per-wave LDS (transpose to A layout), swizzled ----
#pragma unroll
    for (int c = 0; c < 4; c++)
#pragma unroll
      for (int r = 0; r < 4; r++)
        pw[(4 * g + r) * 72 + ((c * 16 + l15) ^ wsw)] = f2bf(s[c][r]);
    bf16x8 pa0 = *(const bf16x8*)(pw + l15 * 72 + (0 * 32 + (g * 8 ^ rsw)));
    bf16x8 pa1 = *(const bf16x8*)(pw + l15 * 72 + (1 * 32 + (g * 8 ^ rsw)));
    // ---- O += P V, V from LDS ----
    const u16* vb2 = vbuf[cur];
#pragma unroll
    for (int n = 0; n < 4; n++) {
      const u16* vp = vb2 + (n * 16 + l15) * 64;
      bf16x8 v0 = *(const bf16x8*)(vp + swz0);
      bf16x8 v1 = *(const bf16x8*)(vp + swz1);
      oacc[n] = __builtin_amdgcn_mfma_f32_16x16x32_bf16(pa0, v0, oacc[n], 0, 0, 0);
      oacc[n] = __builtin_amdgcn_mfma_f32_16x16x32_bf16(pa1, v1, oacc[n], 0, 0, 0);
    }
    // ---- drain stage, flip buffers ----
    asm volatile("s_waitcnt vmcnt(0)" ::: "memory");
    __syncthreads();
  }
  // ---- write O ----
#pragma unroll
  for (int n = 0; n < 4; n++)
#pragma unroll
    for (int r = 0; r < 4; r++) {
      int row = qt * 64 + wave * 16 + g * 4 + r;
      o[((size_t)b * T_ + row) * C_ + h * D_ + n * 16 + l15] =
          f2bf(oacc[n][r] / lrun[r]);
    }
}

extern "C" void kernel_launch(void* const* d_in, const int* in_sizes, int n_in,
                              void* d_out, int out_size, void* d_ws, size_t ws_size,
                              hipStream_t stream) {
  const float* x    = (const float*)d_in[0];
  const int*   mask = (const int*)d_in[1];
  const float* Wq   = (const float*)d_in[2];
  const float* Wk   = (const float*)d_in[3];
  const float* Wv   = (const float*)d_in[4];
  const float* Wo   = (const float*)d_in[5];
  const float* bo   = (const float*)d_in[6];
  const float* ln1g = (const float*)d_in[7];
  const float* ln1b = (const float*)d_in[8];
  const float* ln3g = (const float*)d_in[9];
  const float* ln3b = (const float*)d_in[10];
  const float* W1   = (const float*)d_in[11];
  const float* b1   = (const float*)d_in[12];
  const float* W2   = (const float*)d_in[13];
  const float* b2   = (const float*)d_in[14];
  float* out = (float*)d_out;

  char* ws = (char*)d_ws;
  const size_t MB = 1024 * 1024;
  u16* WqkvT = (u16*)(ws + 0 * MB);   // [3072][1024] (Wq^T | Wk^T | Wv^T)
  u16* WoT   = (u16*)(ws + 6 * MB);   // [1024][1024]
  u16* W1T   = (u16*)(ws + 8 * MB);   // [4096][1024]
  u16* W2T   = (u16*)(ws + 16 * MB);  // [1024][4096]
  u16* xn    = (u16*)(ws + 24 * MB);  // [8192][1024]; dead after QKV -> vT, then hb
  u16* qkv   = (u16*)(ws + 40 * MB);  // [8192][3072] bf16, 48MB
  u16* ob    = (u16*)(ws + 88 * MB);  // [8192][1024]
  float* x2  = (float*)(ws + 104 * MB);  // [8192][1024] f32 -> ends 136MB
  u16* vT  = xn;   // [128][64][1024] bf16, 16MB
  u16* hb  = xn;   // LN3 output
  u16* ff1 = qkv;  // [8192][4096] bf16, 64MB (qkv+ob region, both dead by FF1)

  dim3 b256(256), b512(512);
  // weight transpose + bf16 convert (Wq/Wk/Wv adjacent -> fused [3072][1024])
  trans_f32_bf16<<<dim3(32, 32), b256, 0, stream>>>(Wq, WqkvT, 1024, 1024);
  trans_f32_bf16<<<dim3(32, 32), b256, 0, stream>>>(Wk, WqkvT + 1024 * 1024, 1024, 1024);
  trans_f32_bf16<<<dim3(32, 32), b256, 0, stream>>>(Wv, WqkvT + 2048 * 1024, 1024, 1024);
  trans_f32_bf16<<<dim3(32, 32), b256, 0, stream>>>(Wo, WoT, 1024, 1024);
  trans_f32_bf16<<<dim3(128, 32), b256, 0, stream>>>(W1, W1T, 1024, 4096);
  trans_f32_bf16<<<dim3(32, 128), b256, 0, stream>>>(W2, W2T, 4096, 1024);
  // LN1
  ln_f32_bf16<<<8192, b256, 0, stream>>>(x, ln1g, ln1b, xn);
  // fused QKV projection: [8192][1024] @ [3072][1024]^T -> qkv [8192][3072]
  gemm256<0><<<dim3(12, 32), b512, 0, stream>>>(xn, WqkvT, qkv, nullptr, nullptr, nullptr,
                                                8192, 3072, 1024);
  // V transpose for attention (xn dead; vT aliases it)
  vtrans_bf16<<<dim3(16, 128), b256, 0, stream>>>(qkv, vT);
  // attention
  attn_kernel<<<dim3(16, 128), b256, 0, stream>>>(qkv, vT, mask, ob);
  // output projection + residual -> x2 (f32)
  gemm256<2><<<dim3(4, 32), b512, 0, stream>>>(ob, WoT, nullptr, x2, bo, x, 8192, 1024, 1024);
  // LN3 (vT dead; hb aliases it)
  ln_f32_bf16<<<8192, b256, 0, stream>>>(x2, ln3g, ln3b, hb);
  // FF1: relu(h@W1 + b1)  (qkv+ob dead; ff1 aliases them)
  gemm256<1><<<dim3(16, 32), b512, 0, stream>>>(hb, W1T, ff1, nullptr, b1, nullptr,
                                                8192, 4096, 1024);
  // FF2: x2 + (ff1@W2 + b2) -> out (f32)
  gemm256<2><<<dim3(4, 32), b512, 0, stream>>>(ff1, W2T, nullptr, out, b2, x2,
                                               8192, 1024, 4096);
}

// Round 12
// 614.221 us; speedup vs baseline: 1.1484x; 1.1484x over previous
//
#include <hip/hip_runtime.h>
#include <stdint.h>

typedef unsigned short u16;
typedef __bf16 bf16x8 __attribute__((ext_vector_type(8)));
typedef float f32x4 __attribute__((ext_vector_type(4)));

#define B_ 8
#define T_ 1024
#define C_ 1024
#define H_ 16
#define D_ 64
#define QKS 3072   // fused qkv row stride

__device__ __forceinline__ u16 f2bf(float f) {
  union { float f; unsigned u; } c; c.f = f;
  unsigned u = c.u;
  return (u16)((u + 0x7FFFu + ((u >> 16) & 1u)) >> 16);
}

__device__ __forceinline__ void g2l16(const void* g, void* l) {
  __builtin_amdgcn_global_load_lds((const __attribute__((address_space(1))) void*)g,
                                   (__attribute__((address_space(3))) void*)l, 16, 0, 0);
}

// ---------- transpose f32 [R][C] -> bf16 [C][R] ----------
__global__ __launch_bounds__(256) void trans_f32_bf16(const float* __restrict__ in,
                                                      u16* __restrict__ out, int R, int C) {
  __shared__ float t[32][33];
  int c0 = blockIdx.x * 32, r0 = blockIdx.y * 32;
  int tx = threadIdx.x & 31, ty = threadIdx.x >> 5;
#pragma unroll
  for (int i = ty; i < 32; i += 8)
    t[i][tx] = in[(size_t)(r0 + i) * C + c0 + tx];
  __syncthreads();
#pragma unroll
  for (int i = ty; i < 32; i += 8)
    out[(size_t)(c0 + i) * R + r0 + tx] = f2bf(t[tx][i]);
}

// ---------- transpose V: qkv [B*T][3072] (v section) -> vt [B*H][D][T] ----------
__global__ __launch_bounds__(256) void vtrans_bf16(const u16* __restrict__ qkv,
                                                   u16* __restrict__ vt) {
  __shared__ u16 t[64][66];
  int bh = blockIdx.y;
  int b = bh >> 4, h = bh & 15;
  int t0 = blockIdx.x * 64;
  int tx = threadIdx.x & 63, w = threadIdx.x >> 6;
#pragma unroll
  for (int i = w; i < 64; i += 4)
    t[i][tx] = qkv[(size_t)(b * T_ + t0 + i) * QKS + 2048 + h * D_ + tx];
  __syncthreads();
#pragma unroll
  for (int d = w; d < 64; d += 4)
    vt[((size_t)bh * D_ + d) * T_ + t0 + tx] = t[tx][d];
}

// ---------- layernorm f32 [rows][1024] -> bf16 ----------
__global__ __launch_bounds__(256) void ln_f32_bf16(const float* __restrict__ x,
                                                   const float* __restrict__ g,
                                                   const float* __restrict__ bt,
                                                   u16* __restrict__ out) {
  int row = blockIdx.x, tid = threadIdx.x;
  const float4* xr = (const float4*)(x + (size_t)row * C_);
  float4 a = xr[tid];
  float s = a.x + a.y + a.z + a.w;
  float ss = a.x * a.x + a.y * a.y + a.z * a.z + a.w * a.w;
#pragma unroll
  for (int m = 1; m < 64; m <<= 1) { s += __shfl_xor(s, m); ss += __shfl_xor(ss, m); }
  __shared__ float red[8];
  int wave = tid >> 6, lane = tid & 63;
  if (lane == 0) { red[wave] = s; red[wave + 4] = ss; }
  __syncthreads();
  s = red[0] + red[1] + red[2] + red[3];
  ss = red[4] + red[5] + red[6] + red[7];
  float mean = s * (1.0f / C_);
  float rstd = rsqrtf(ss * (1.0f / C_) - mean * mean + 1e-5f);
  float4 gg = ((const float4*)g)[tid];
  float4 bb = ((const float4*)bt)[tid];
  u16* op = out + (size_t)row * C_ + tid * 4;
  op[0] = f2bf((a.x - mean) * rstd * gg.x + bb.x);
  op[1] = f2bf((a.y - mean) * rstd * gg.y + bb.y);
  op[2] = f2bf((a.z - mean) * rstd * gg.z + bb.z);
  op[3] = f2bf((a.w - mean) * rstd * gg.w + bb.w);
}

// ---------- GEMM 128x128 (measured-good R7 structure): A[M][K] @ (BT[N][K])^T ----------
// EPI 0: plain -> bf16.  EPI 1: +bias, relu -> bf16.  EPI 2: +bias +resid -> f32.
template <int EPI>
__global__ __launch_bounds__(256) void gemm_bf16(const u16* __restrict__ A,
                                                 const u16* __restrict__ BT,
                                                 u16* __restrict__ outb, float* __restrict__ outf,
                                                 const float* __restrict__ bias,
                                                 const float* __restrict__ resid,
                                                 int M, int N, int K) {
  __shared__ u16 As[128 * 32];
  __shared__ u16 Bs[128 * 32];
  int tid = threadIdx.x, wave = tid >> 6, lane = tid & 63;
  int m0 = blockIdx.y * 128, n0 = blockIdx.x * 128;
  int wr = wave >> 1, wc = wave & 1;
  int frow = lane & 15, fk = (lane >> 4) * 8;
  f32x4 acc[4][4] = {};
  for (int k0 = 0; k0 < K; k0 += 32) {
    __syncthreads();
#pragma unroll
    for (int i = 0; i < 2; i++) {
      int c = i * 256 + tid;
      const u16* ga = A + (size_t)(m0 + (c >> 2)) * K + k0 + (c & 3) * 8;
      const u16* gb = BT + (size_t)(n0 + (c >> 2)) * K + k0 + (c & 3) * 8;
      g2l16(ga, As + (i * 256 + wave * 64) * 8);
      g2l16(gb, Bs + (i * 256 + wave * 64) * 8);
    }
    asm volatile("s_waitcnt vmcnt(0)" ::: "memory");
    __syncthreads();
    bf16x8 af[4], bfr[4];
#pragma unroll
    for (int m = 0; m < 4; m++) af[m] = *(const bf16x8*)(As + (wr * 64 + m * 16 + frow) * 32 + fk);
#pragma unroll
    for (int n = 0; n < 4; n++) bfr[n] = *(const bf16x8*)(Bs + (wc * 64 + n * 16 + frow) * 32 + fk);
#pragma unroll
    for (int m = 0; m < 4; m++)
#pragma unroll
      for (int n = 0; n < 4; n++)
        acc[m][n] = __builtin_amdgcn_mfma_f32_16x16x32_bf16(af[m], bfr[n], acc[m][n], 0, 0, 0);
  }
#pragma unroll
  for (int m = 0; m < 4; m++)
#pragma unroll
    for (int n = 0; n < 4; n++)
#pragma unroll
      for (int r = 0; r < 4; r++) {
        int row = m0 + wr * 64 + m * 16 + (lane >> 4) * 4 + r;
        int col = n0 + wc * 64 + n * 16 + (lane & 15);
        float v = acc[m][n][r];
        if (EPI == 0) {
          outb[(size_t)row * N + col] = f2bf(v);
        } else if (EPI == 1) {
          v += bias[col];
          v = fmaxf(v, 0.f);
          outb[(size_t)row * N + col] = f2bf(v);
        } else {
          v += bias[col] + resid[(size_t)row * N + col];
          outf[(size_t)row * N + col] = v;
        }
      }
}

// ---------- flash attention, LDS double-buffered pipeline (measured: 135us) ----------
// qkv bf16 [B*T][3072] (q at col 0, k at col 1024); vt [B*H][D][T]; KVBLK=64.
__global__ __launch_bounds__(256) void attn_kernel(const u16* __restrict__ qkv,
                                                   const u16* __restrict__ vt,
                                                   const int* __restrict__ mask,
                                                   u16* __restrict__ o) {
  __shared__ __attribute__((aligned(16))) u16 kbuf[2][64 * 64];
  __shared__ __attribute__((aligned(16))) u16 vbuf[2][64 * 64];
  __shared__ __attribute__((aligned(16))) u16 plds[4][16 * 72];

  int tid = threadIdx.x, wave = tid >> 6, lane = tid & 63;
  int qt = blockIdx.x;           // 0..15  (64 q rows per block)
  int bh = blockIdx.y;           // 0..127
  int b = bh >> 4, h = bh & 15;
  int l15 = lane & 15, g = lane >> 4;

  int qrow = qt * 64 + wave * 16 + l15;
  int dk = g * 8;
  const u16* qp = qkv + (size_t)(b * T_ + qrow) * QKS + h * D_;
  bf16x8 qf0 = *(const bf16x8*)(qp + dk);
  bf16x8 qf1 = *(const bf16x8*)(qp + dk + 32);

  const u16* vtb = vt + (size_t)bh * D_ * T_;   // [64][1024]
  const size_t kbase = (size_t)(b * T_) * QKS + 1024 + h * D_;

  int c0 = tid, r0s = c0 >> 3, cc0 = c0 & 7, sc0 = cc0 ^ (r0s & 7);
  int c1 = 256 + tid, r1s = c1 >> 3, cc1 = c1 & 7, sc1 = cc1 ^ (r1s & 7);
  const u16* ksrc0 = qkv + kbase + (size_t)r0s * QKS + sc0 * 8;
  const u16* ksrc1 = qkv + kbase + (size_t)r1s * QKS + sc1 * 8;
  const u16* vsrc0 = vtb + (size_t)r0s * T_ + sc0 * 8;
  const u16* vsrc1 = vtb + (size_t)r1s * T_ + sc1 * 8;
  int dst0 = (0 * 256 + wave * 64) * 8;
  int dst1 = (1 * 256 + wave * 64) * 8;

  f32x4 oacc[4] = {};
  float mrun[4], lrun[4];
#pragma unroll
  for (int r = 0; r < 4; r++) { mrun[r] = -1e30f; lrun[r] = 0.f; }

  u16* pw = plds[wave];
  const int wsw = g * 8;                  // P write xor
  const int rsw = ((l15 >> 2) & 3) * 8;   // P read xor
  const int swz0 = (g ^ (l15 & 7)) * 8;        // K/V tile read swizzle, chunk g
  const int swz1 = ((g + 4) ^ (l15 & 7)) * 8;  // chunk g+4

  // prologue: stage tile 0 into buf 0
  {
    g2l16(ksrc0, kbuf[0] + dst0);
    g2l16(ksrc1, kbuf[0] + dst1);
    g2l16(vsrc0, vbuf[0] + dst0);
    g2l16(vsrc1, vbuf[0] + dst1);
  }
  asm volatile("s_waitcnt vmcnt(0)" ::: "memory");
  __syncthreads();

  for (int kt = 0; kt < T_ / 64; ++kt) {
    int cur = kt & 1;
    if (kt < T_ / 64 - 1) {
      int nxt = cur ^ 1;
      size_t ko = (size_t)(kt + 1) * 64 * QKS;
      size_t vo = (size_t)(kt + 1) * 64;
      g2l16(ksrc0 + ko, kbuf[nxt] + dst0);
      g2l16(ksrc1 + ko, kbuf[nxt] + dst1);
      g2l16(vsrc0 + vo, vbuf[nxt] + dst0);
      g2l16(vsrc1 + vo, vbuf[nxt] + dst1);
    }
    int mv[4];
#pragma unroll
    for (int c = 0; c < 4; c++) mv[c] = mask[b * T_ + kt * 64 + c * 16 + l15];

    const u16* kb = kbuf[cur];
    f32x4 s[4];
#pragma unroll
    for (int c = 0; c < 4; c++) {
      const u16* kp = kb + (c * 16 + l15) * 64;
      bf16x8 k0 = *(const bf16x8*)(kp + swz0);
      bf16x8 k1 = *(const bf16x8*)(kp + swz1);
      f32x4 a = {};
      a = __builtin_amdgcn_mfma_f32_16x16x32_bf16(qf0, k0, a, 0, 0, 0);
      a = __builtin_amdgcn_mfma_f32_16x16x32_bf16(qf1, k1, a, 0, 0, 0);
#pragma unroll
      for (int r = 0; r < 4; r++) a[r] = mv[c] ? a[r] * 0.125f : -1e30f;
      s[c] = a;
    }
    float tmax[4];
#pragma unroll
    for (int r = 0; r < 4; r++)
      tmax[r] = fmaxf(fmaxf(s[0][r], s[1][r]), fmaxf(s[2][r], s[3][r]));
#pragma unroll
    for (int m = 1; m < 16; m <<= 1)
#pragma unroll
      for (int r = 0; r < 4; r++) tmax[r] = fmaxf(tmax[r], __shfl_xor(tmax[r], m));
    float alpha[4];
#pragma unroll
    for (int r = 0; r < 4; r++) {
      float nm = fmaxf(mrun[r], tmax[r]);
      alpha[r] = __expf(mrun[r] - nm);
      mrun[r] = nm;
    }
    float psum[4] = {0.f, 0.f, 0.f, 0.f};
#pragma unroll
    for (int c = 0; c < 4; c++)
#pragma unroll
      for (int r = 0; r < 4; r++) {
        float p = __expf(s[c][r] - mrun[r]);
        s[c][r] = p;
        psum[r] += p;
      }
#pragma unroll
    for (int m = 1; m < 16; m <<= 1)
#pragma unroll
      for (int r = 0; r < 4; r++) psum[r] += __shfl_xor(psum[r], m);
#pragma unroll
    for (int r = 0; r < 4; r++) lrun[r] = lrun[r] * alpha[r] + psum[r];
#pragma unroll
    for (int n = 0; n < 4; n++)
#pragma unroll
      for (int r = 0; r < 4; r++) oacc[n][r] *= alpha[r];
#pragma unroll
    for (int c = 0; c < 4; c++)
#pragma unroll
      for (int r = 0; r < 4; r++)
        pw[(4 * g + r) * 72 + ((c * 16 + l15) ^ wsw)] = f2bf(s[c][r]);
    bf16x8 pa0 = *(const bf16x8*)(pw + l15 * 72 + (0 * 32 + (g * 8 ^ rsw)));
    bf16x8 pa1 = *(const bf16x8*)(pw + l15 * 72 + (1 * 32 + (g * 8 ^ rsw)));
    const u16* vb2 = vbuf[cur];
#pragma unroll
    for (int n = 0; n < 4; n++) {
      const u16* vp = vb2 + (n * 16 + l15) * 64;
      bf16x8 v0 = *(const bf16x8*)(vp + swz0);
      bf16x8 v1 = *(const bf16x8*)(vp + swz1);
      oacc[n] = __builtin_amdgcn_mfma_f32_16x16x32_bf16(pa0, v0, oacc[n], 0, 0, 0);
      oacc[n] = __builtin_amdgcn_mfma_f32_16x16x32_bf16(pa1, v1, oacc[n], 0, 0, 0);
    }
    asm volatile("s_waitcnt vmcnt(0)" ::: "memory");
    __syncthreads();
  }
#pragma unroll
  for (int n = 0; n < 4; n++)
#pragma unroll
    for (int r = 0; r < 4; r++) {
      int row = qt * 64 + wave * 16 + g * 4 + r;
      o[((size_t)b * T_ + row) * C_ + h * D_ + n * 16 + l15] =
          f2bf(oacc[n][r] / lrun[r]);
    }
}

extern "C" void kernel_launch(void* const* d_in, const int* in_sizes, int n_in,
                              void* d_out, int out_size, void* d_ws, size_t ws_size,
                              hipStream_t stream) {
  const float* x    = (const float*)d_in[0];
  const int*   mask = (const int*)d_in[1];
  const float* Wq   = (const float*)d_in[2];
  const float* Wk   = (const float*)d_in[3];
  const float* Wv   = (const float*)d_in[4];
  const float* Wo   = (const float*)d_in[5];
  const float* bo   = (const float*)d_in[6];
  const float* ln1g = (const float*)d_in[7];
  const float* ln1b = (const float*)d_in[8];
  const float* ln3g = (const float*)d_in[9];
  const float* ln3b = (const float*)d_in[10];
  const float* W1   = (const float*)d_in[11];
  const float* b1   = (const float*)d_in[12];
  const float* W2   = (const float*)d_in[13];
  const float* b2   = (const float*)d_in[14];
  float* out = (float*)d_out;

  char* ws = (char*)d_ws;
  const size_t MB = 1024 * 1024;
  u16* WqkvT = (u16*)(ws + 0 * MB);   // [3072][1024] (Wq^T | Wk^T | Wv^T)
  u16* WoT   = (u16*)(ws + 6 * MB);   // [1024][1024]
  u16* W1T   = (u16*)(ws + 8 * MB);   // [4096][1024]
  u16* W2T   = (u16*)(ws + 16 * MB);  // [1024][4096]
  u16* xn    = (u16*)(ws + 24 * MB);  // [8192][1024]; dead after QKV -> vT, then hb
  u16* qkv   = (u16*)(ws + 40 * MB);  // [8192][3072] bf16, 48MB
  u16* ob    = (u16*)(ws + 88 * MB);  // [8192][1024]
  float* x2  = (float*)(ws + 104 * MB);  // [8192][1024] f32 -> ends 136MB
  u16* vT  = xn;   // [128][64][1024] bf16, 16MB
  u16* hb  = xn;   // LN3 output
  u16* ff1 = qkv;  // [8192][4096] bf16, 64MB (qkv+ob region, both dead by FF1)

  dim3 b256(256);
  // weight transpose + bf16 convert (Wq/Wk/Wv -> fused [3072][1024])
  trans_f32_bf16<<<dim3(32, 32), b256, 0, stream>>>(Wq, WqkvT, 1024, 1024);
  trans_f32_bf16<<<dim3(32, 32), b256, 0, stream>>>(Wk, WqkvT + 1024 * 1024, 1024, 1024);
  trans_f32_bf16<<<dim3(32, 32), b256, 0, stream>>>(Wv, WqkvT + 2048 * 1024, 1024, 1024);
  trans_f32_bf16<<<dim3(32, 32), b256, 0, stream>>>(Wo, WoT, 1024, 1024);
  trans_f32_bf16<<<dim3(128, 32), b256, 0, stream>>>(W1, W1T, 1024, 4096);
  trans_f32_bf16<<<dim3(32, 128), b256, 0, stream>>>(W2, W2T, 4096, 1024);
  // LN1
  ln_f32_bf16<<<8192, b256, 0, stream>>>(x, ln1g, ln1b, xn);
  // fused QKV projection: [8192][1024] @ [3072][1024]^T -> qkv [8192][3072], 1536 blocks
  gemm_bf16<0><<<dim3(24, 64), b256, 0, stream>>>(xn, WqkvT, qkv, nullptr, nullptr, nullptr,
                                                  8192, 3072, 1024);
  // V transpose for attention (xn dead; vT aliases it)
  vtrans_bf16<<<dim3(16, 128), b256, 0, stream>>>(qkv, vT);
  // attention
  attn_kernel<<<dim3(16, 128), b256, 0, stream>>>(qkv, vT, mask, ob);
  // output projection + residual -> x2 (f32), 512 blocks
  gemm_bf16<2><<<dim3(8, 64), b256, 0, stream>>>(ob, WoT, nullptr, x2, bo, x, 8192, 1024, 1024);
  // LN3 (vT dead; hb aliases it)
  ln_f32_bf16<<<8192, b256, 0, stream>>>(x2, ln3g, ln3b, hb);
  // FF1: relu(h@W1 + b1), 2048 blocks
  gemm_bf16<1><<<dim3(32, 64), b256, 0, stream>>>(hb, W1T, ff1, nullptr, b1, nullptr,
                                                  8192, 4096, 1024);
  // FF2: x2 + (ff1@W2 + b2) -> out (f32), 512 blocks
  gemm_bf16<2><<<dim3(8, 64), b256, 0, stream>>>(ff1, W2T, nullptr, out, b2, x2,
                                                 8192, 1024, 4096);
}